// Round 2
// baseline (342.734 us; speedup 1.0000x reference)
//
#include <hip/hip_runtime.h>
#include <stdint.h>

// Problem constants (compile-time; mem_size input ignored, == 128)
#define B_SZ 32
#define L_SZ 641
#define C_SZ 768
#define H_SZ 12
#define HD 64
#define MEMK 128
#define M_REAL (B_SZ * L_SZ)   // 20512
#define M_PAD 20608            // 161 * 128
#define N_QKV (3 * C_SZ)       // 2304
#define NQT 11                 // ceil(641/64)
#define QK_STRIDE 1536         // qkv buffer holds only Q,K
#define VT_STRIDE 648          // vt row stride (key dim), 8-mult for 16B-aligned short8
#define SCL_LOG2E 0.18033688f  // (1/sqrt(64)) * log2(e)

typedef __attribute__((ext_vector_type(8))) short short8;
typedef __attribute__((ext_vector_type(4))) float f32x4;
typedef __attribute__((ext_vector_type(4))) unsigned short ushort4v;

__device__ inline unsigned short f2bf(float x) {
  union { float f; uint32_t u; } v; v.f = x;
  uint32_t r = v.u + 0x7fffu + ((v.u >> 16) & 1u);
  return (unsigned short)(r >> 16);
}

__device__ inline void gload_lds16(const void* g, void* l) {
  __builtin_amdgcn_global_load_lds(
      (const __attribute__((address_space(1))) uint32_t*)g,
      (__attribute__((address_space(3))) uint32_t*)l, 16, 0, 0);
}

// ---------------- conversion kernels ----------------
__global__ __launch_bounds__(256) void k_conv_x(const float* __restrict__ src,
                                                unsigned short* __restrict__ dst,
                                                int n4) {
  int i = blockIdx.x * 256 + threadIdx.x;
  if (i >= n4) return;
  float4 v = *(const float4*)(src + (size_t)i * 4);
  ushort4v o = { f2bf(v.x), f2bf(v.y), f2bf(v.z), f2bf(v.w) };
  *(ushort4v*)(dst + (size_t)i * 4) = o;
}

// dst[c][r] = bf16(src[r][c]); R, Ccol multiples of 32
__global__ __launch_bounds__(256) void k_transpose_bf16(const float* __restrict__ src,
                                                        unsigned short* __restrict__ dst,
                                                        int R, int Ccol) {
  __shared__ float tile[32][33];
  int c0 = blockIdx.x * 32, r0 = blockIdx.y * 32;
  int tx = threadIdx.x & 31, ty = threadIdx.x >> 5;
  for (int i = ty; i < 32; i += 8)
    tile[i][tx] = src[(size_t)(r0 + i) * Ccol + c0 + tx];
  __syncthreads();
  for (int i = ty; i < 32; i += 8)
    dst[(size_t)(c0 + i) * R + r0 + tx] = f2bf(tile[tx][i]);
}

// ---------------- GEMM: C[m][n] = sum_k A[m][k]*Bt[n][k] ----------------
// A: [*][K] bf16, Bt: [N][K] bf16.  128x128 tile, BK=64, 4 waves.
// MODE 0: f32 out, stride N.
// MODE 2: qkv split epilogue: n<1536 -> bf16 out stride 1536; n>=1536 -> V
//         transposed into vt[(b*12+h)*64 + d][key] (stride VT_STRIDE).
template <int MODE>
__global__ __launch_bounds__(256) void k_gemm(const short* __restrict__ A,
                                              const short* __restrict__ Bt,
                                              void* __restrict__ Cp,
                                              short* __restrict__ vt,
                                              int Mreal, int N, int K) {
  __shared__ short As[128 * 64];
  __shared__ short Bs[128 * 64];
  const int tiles_n = N >> 7;
  int tm = blockIdx.x / tiles_n, tn = blockIdx.x % tiles_n;
  int m0 = tm << 7, n0 = tn << 7;
  int lane = threadIdx.x & 63, wave = threadIdx.x >> 6;
  int wr = wave >> 1, wc = wave & 1;
  int l15 = lane & 15, g = lane >> 4;

  f32x4 acc[4][4];
  f32x4 z = {0.f, 0.f, 0.f, 0.f};
#pragma unroll
  for (int i = 0; i < 4; ++i)
#pragma unroll
    for (int j = 0; j < 4; ++j) acc[i][j] = z;

  int arow = lane >> 3;          // 0..7 rows within 8-row chunk
  int acol = (lane & 7) * 8;     // elem offset within 64

  for (int k0 = 0; k0 < K; k0 += 64) {
    __syncthreads();
#pragma unroll
    for (int cc = 0; cc < 4; ++cc) {
      int rb = (cc * 4 + wave) * 8;  // wave-uniform row base
      gload_lds16(A + (size_t)(m0 + rb + arow) * K + (k0 + acol),
                  (char*)As + rb * 128);
      gload_lds16(Bt + (size_t)(n0 + rb + arow) * K + (k0 + acol),
                  (char*)Bs + rb * 128);
    }
    __syncthreads();
#pragma unroll
    for (int ks = 0; ks < 2; ++ks) {
      short8 a[4], b[4];
#pragma unroll
      for (int mf = 0; mf < 4; ++mf)
        a[mf] = *(const short8*)&As[(wr * 64 + mf * 16 + l15) * 64 + ks * 32 + g * 8];
#pragma unroll
      for (int nf = 0; nf < 4; ++nf)
        b[nf] = *(const short8*)&Bs[(wc * 64 + nf * 16 + l15) * 64 + ks * 32 + g * 8];
#pragma unroll
      for (int mf = 0; mf < 4; ++mf)
#pragma unroll
        for (int nf = 0; nf < 4; ++nf)
          acc[mf][nf] = __builtin_amdgcn_mfma_f32_16x16x32_bf16(a[mf], b[nf], acc[mf][nf], 0, 0, 0);
    }
  }
  // epilogue: D row = g*4+reg, col = l15 (m89-verified layout)
  if (MODE == 2 && n0 >= 1536) {
    // V block: scatter transposed into vt
    int hq = (n0 + wc * 64 - 1536) >> 6;  // head, uniform per wave
#pragma unroll
    for (int mf = 0; mf < 4; ++mf) {
#pragma unroll
      for (int reg = 0; reg < 4; ++reg) {
        int m = m0 + wr * 64 + mf * 16 + g * 4 + reg;
        if (m >= Mreal) continue;
        int bb = (unsigned)m / 641u;
        int key = m - bb * 641;
        size_t rbase = ((size_t)(bb * H_SZ + hq) * HD) * VT_STRIDE + key;
#pragma unroll
        for (int nf = 0; nf < 4; ++nf) {
          int d = nf * 16 + l15;  // 0..63
          vt[rbase + (size_t)d * VT_STRIDE] = f2bf(acc[mf][nf][reg]);
        }
      }
    }
    return;
  }
#pragma unroll
  for (int mf = 0; mf < 4; ++mf) {
#pragma unroll
    for (int reg = 0; reg < 4; ++reg) {
      int m = m0 + wr * 64 + mf * 16 + g * 4 + reg;
      if (m >= Mreal) continue;
#pragma unroll
      for (int nf = 0; nf < 4; ++nf) {
        int n = n0 + wc * 64 + nf * 16 + l15;
        float v = acc[mf][nf][reg];
        if (MODE == 2)
          ((unsigned short*)Cp)[(size_t)m * QK_STRIDE + n] = f2bf(v);
        else
          ((float*)Cp)[(size_t)m * N + n] = v;
      }
    }
  }
}

// ---------------- fused masked attention ----------------
// grid: B*H*NQT = 4224 blocks (8*528, XCD-swizzled), 256 threads (4 waves x 16 q-rows)
__global__ __launch_bounds__(256) void k_attn(const short* __restrict__ qk,  // [M][1536]
                                              const short* __restrict__ vt,  // [384*64][648]
                                              short* __restrict__ y) {       // [M_PAD][768]
  __shared__ short Ks[64 * 72];       // K tile row-major [key][d]
  __shared__ short Vt[64 * 72];       // V^T tile [d][key]
  __shared__ short Ps[4][16 * 72];    // per-wave P [q][key]

  // XCD swizzle: launch-id bid lands on XCD bid&7; give each XCD a contiguous
  // chunk of 528 work items = 48 whole (b,h) groups -> K/V L2 reuse.
  int bid = blockIdx.x;
  int work = (bid & 7) * 528 + (bid >> 3);
  int qt = work % NQT;
  int rem = work / NQT;
  int h = rem % H_SZ;
  int b = rem / H_SZ;
  int q0 = qt * 64;
  int lane = threadIdx.x & 63, w = threadIdx.x >> 6;
  int l15 = lane & 15, g = lane >> 4;

  // Q fragments in registers (A-frag: row = l15, k = g*8+i, per 32-wide kstep)
  size_t qbase = (size_t)(b * L_SZ + q0 + w * 16 + l15) * QK_STRIDE + h * HD;
  short8 qa[2];
#pragma unroll
  for (int ks = 0; ks < 2; ++ks)
    qa[ks] = *(const short8*)&qk[qbase + ks * 32 + g * 8];

  f32x4 o[4];
  float m_run[4], l_run[4];
  f32x4 z = {0.f, 0.f, 0.f, 0.f};
#pragma unroll
  for (int df = 0; df < 4; ++df) o[df] = z;
#pragma unroll
  for (int r = 0; r < 4; ++r) { m_run[r] = -1e30f; l_run[r] = 0.f; }

  // per-row mask bound, hoisted: valid j <= jmax[reg]
  int jmax[4];
#pragma unroll
  for (int reg = 0; reg < 4; ++reg) {
    int i = q0 + w * 16 + g * 4 + reg;
    jmax[reg] = (i == MEMK) ? (L_SZ - 1) : (i < MEMK ? MEMK : i);
  }

  int q1 = q0 + 63; if (q1 > L_SZ - 1) q1 = L_SZ - 1;
  int col_max = (q0 <= MEMK && MEMK <= q1) ? (L_SZ - 1) : (q1 < MEMK ? MEMK : q1);

  size_t kbase = (size_t)b * L_SZ * QK_STRIDE + C_SZ + h * HD;
  size_t vbase = (size_t)(b * H_SZ + h) * HD * VT_STRIDE;

  for (int c0 = 0; c0 <= col_max; c0 += 64) {
    __syncthreads();
    // stage K rows [c0, c0+64): coalesced short8, minimal-conflict b128 writes
#pragma unroll
    for (int it = 0; it < 2; ++it) {
      int idx = threadIdx.x + it * 256;
      int kk = idx >> 3, j = (idx & 7) * 8;
      *(short8*)&Ks[kk * 72 + j] =
          *(const short8*)&qk[kbase + (size_t)(c0 + kk) * QK_STRIDE + j];
    }
    // stage V^T from pre-transposed global: symmetric with K
#pragma unroll
    for (int it = 0; it < 2; ++it) {
      int idx = threadIdx.x + it * 256;
      int d = idx >> 3, key0 = (idx & 7) * 8;
      *(short8*)&Vt[d * 72 + key0] =
          *(const short8*)&vt[vbase + (size_t)d * VT_STRIDE + c0 + key0];
    }
    __syncthreads();

    // S = Q K^T  (D: row=q=g*4+reg, col=key=l15 within each 16-wide kf frag)
    f32x4 s[4];
#pragma unroll
    for (int kf = 0; kf < 4; ++kf) {
      f32x4 sa = z;
#pragma unroll
      for (int ks = 0; ks < 2; ++ks) {
        short8 kb = *(const short8*)&Ks[(kf * 16 + l15) * 72 + ks * 32 + g * 8];
        sa = __builtin_amdgcn_mfma_f32_16x16x32_bf16(qa[ks], kb, sa, 0, 0, 0);
      }
      s[kf] = sa;
    }

    // mask + scale into log2 domain
#pragma unroll
    for (int kf = 0; kf < 4; ++kf) {
      int j = c0 + kf * 16 + l15;
#pragma unroll
      for (int reg = 0; reg < 4; ++reg)
        s[kf][reg] = (j <= jmax[reg]) ? s[kf][reg] * SCL_LOG2E : -1e30f;
    }

    // online softmax in exp2 domain (stats per row; keys spread over 16-lane group)
    float corr[4];
#pragma unroll
    for (int reg = 0; reg < 4; ++reg) {
      float t = fmaxf(fmaxf(s[0][reg], s[1][reg]), fmaxf(s[2][reg], s[3][reg]));
      t = fmaxf(t, __shfl_xor(t, 1));
      t = fmaxf(t, __shfl_xor(t, 2));
      t = fmaxf(t, __shfl_xor(t, 4));
      t = fmaxf(t, __shfl_xor(t, 8));
      float mn = fmaxf(m_run[reg], t);
      corr[reg] = exp2f(m_run[reg] - mn);
      m_run[reg] = mn;
    }
#pragma unroll
    for (int kf = 0; kf < 4; ++kf)
#pragma unroll
      for (int reg = 0; reg < 4; ++reg)
        s[kf][reg] = exp2f(s[kf][reg] - m_run[reg]);
#pragma unroll
    for (int reg = 0; reg < 4; ++reg) {
      float ls = s[0][reg] + s[1][reg] + s[2][reg] + s[3][reg];
      ls += __shfl_xor(ls, 1);
      ls += __shfl_xor(ls, 2);
      ls += __shfl_xor(ls, 4);
      ls += __shfl_xor(ls, 8);
      l_run[reg] = l_run[reg] * corr[reg] + ls;
      o[0][reg] *= corr[reg];
      o[1][reg] *= corr[reg];
      o[2][reg] *= corr[reg];
      o[3][reg] *= corr[reg];
    }

    // P -> per-wave LDS (bf16); in-wave write->read ordered by lgkmcnt, no barrier
#pragma unroll
    for (int kf = 0; kf < 4; ++kf)
#pragma unroll
      for (int reg = 0; reg < 4; ++reg)
        Ps[w][(g * 4 + reg) * 72 + kf * 16 + l15] = (short)f2bf(s[kf][reg]);

    short8 pa[2];
#pragma unroll
    for (int ks = 0; ks < 2; ++ks)
      pa[ks] = *(const short8*)&Ps[w][l15 * 72 + ks * 32 + g * 8];
#pragma unroll
    for (int df = 0; df < 4; ++df) {
#pragma unroll
      for (int ks = 0; ks < 2; ++ks) {
        short8 vb = *(const short8*)&Vt[(df * 16 + l15) * 72 + ks * 32 + g * 8];
        o[df] = __builtin_amdgcn_mfma_f32_16x16x32_bf16(pa[ks], vb, o[df], 0, 0, 0);
      }
    }
  }

  // epilogue
#pragma unroll
  for (int reg = 0; reg < 4; ++reg) {
    int i = q0 + w * 16 + g * 4 + reg;
    if (i >= L_SZ) continue;
    float inv = 1.0f / l_run[reg];
#pragma unroll
    for (int df = 0; df < 4; ++df)
      y[(size_t)(b * L_SZ + i) * C_SZ + h * HD + df * 16 + l15] = (short)f2bf(o[df][reg] * inv);
  }
}

// ---------------- launch ----------------
extern "C" void kernel_launch(void* const* d_in, const int* in_sizes, int n_in,
                              void* d_out, int out_size, void* d_ws, size_t ws_size,
                              hipStream_t stream) {
  const float* x = (const float*)d_in[0];
  const float* Wa = (const float*)d_in[1];
  const float* Wp = (const float*)d_in[2];
  float* out = (float*)d_out;

  char* ws = (char*)d_ws;
  size_t off0 = 0;
  short* x_bf = (short*)(ws + off0);                       // [M_PAD][768], reused as y
  size_t off1 = off0 + (size_t)M_PAD * C_SZ * 2;
  short* Wa_t = (short*)(ws + off1);                       // [2304][768]
  size_t off2 = off1 + (size_t)N_QKV * C_SZ * 2;
  short* Wp_t = (short*)(ws + off2);                       // [768][768]
  size_t off3 = off2 + (size_t)C_SZ * C_SZ * 2;
  short* qk = (short*)(ws + off3);                         // [M_REAL][1536] (Q,K only)
  size_t off4 = off3 + (size_t)M_REAL * QK_STRIDE * 2;
  short* vt = (short*)(ws + off4);                         // [384*64][648] V transposed
  size_t need = off4 + (size_t)B_SZ * H_SZ * HD * VT_STRIDE * 2 + 4096;  // +4KB slack for
  if (ws_size < need) return;  // ~131.2 MB             // masked OOB-in-row reads at c0=640

  int n4 = M_REAL * C_SZ / 4;
  k_conv_x<<<(n4 + 255) / 256, 256, 0, stream>>>(x, (unsigned short*)x_bf, n4);
  k_transpose_bf16<<<dim3(N_QKV / 32, C_SZ / 32), 256, 0, stream>>>(Wa, (unsigned short*)Wa_t, C_SZ, N_QKV);
  k_transpose_bf16<<<dim3(C_SZ / 32, C_SZ / 32), 256, 0, stream>>>(Wp, (unsigned short*)Wp_t, C_SZ, C_SZ);

  k_gemm<2><<<(M_PAD / 128) * (N_QKV / 128), 256, 0, stream>>>(x_bf, Wa_t, (void*)qk, vt, M_REAL, N_QKV, C_SZ);
  k_attn<<<B_SZ * H_SZ * NQT, 256, 0, stream>>>(qk, vt, x_bf /* y reuses x_bf */);
  k_gemm<0><<<(M_PAD / 128) * (C_SZ / 128), 256, 0, stream>>>(x_bf, Wp_t, (void*)out, nullptr, M_REAL, C_SZ, C_SZ);
}

// Round 3
// 319.404 us; speedup vs baseline: 1.0730x; 1.0730x over previous
//
#include <hip/hip_runtime.h>
#include <stdint.h>

// Problem constants (compile-time; mem_size input ignored, == 128)
#define B_SZ 32
#define L_SZ 641
#define C_SZ 768
#define H_SZ 12
#define HD 64
#define MEMK 128
#define M_REAL (B_SZ * L_SZ)   // 20512
#define M_PAD 20608            // 161 * 128
#define N_QKV (3 * C_SZ)       // 2304
#define NQT 11                 // ceil(641/64)
#define QK_STRIDE 1536         // qk buffer holds only Q,K
#define VT_STRIDE 648          // vt row stride (key dim), 8-mult for 16B-aligned short8
#define SCL_LOG2E 0.18033688f  // (1/sqrt(64)) * log2(e)

typedef __attribute__((ext_vector_type(8))) short short8;
typedef __attribute__((ext_vector_type(4))) float f32x4;
typedef __attribute__((ext_vector_type(4))) unsigned short ushort4v;

__device__ inline unsigned short f2bf(float x) {
  union { float f; uint32_t u; } v; v.f = x;
  uint32_t r = v.u + 0x7fffu + ((v.u >> 16) & 1u);
  return (unsigned short)(r >> 16);
}

__device__ inline void gload_lds16(const void* g, void* l) {
  __builtin_amdgcn_global_load_lds(
      (const __attribute__((address_space(1))) uint32_t*)g,
      (__attribute__((address_space(3))) uint32_t*)l, 16, 0, 0);
}

// ---------------- conversion kernels ----------------
__global__ __launch_bounds__(256) void k_conv_x(const float* __restrict__ src,
                                                unsigned short* __restrict__ dst,
                                                int n4) {
  int i = blockIdx.x * 256 + threadIdx.x;
  if (i >= n4) return;
  float4 v = *(const float4*)(src + (size_t)i * 4);
  ushort4v o = { f2bf(v.x), f2bf(v.y), f2bf(v.z), f2bf(v.w) };
  *(ushort4v*)(dst + (size_t)i * 4) = o;
}

// dst[c][r] = bf16(src[r][c]); R, Ccol multiples of 32
__global__ __launch_bounds__(256) void k_transpose_bf16(const float* __restrict__ src,
                                                        unsigned short* __restrict__ dst,
                                                        int R, int Ccol) {
  __shared__ float tile[32][33];
  int c0 = blockIdx.x * 32, r0 = blockIdx.y * 32;
  int tx = threadIdx.x & 31, ty = threadIdx.x >> 5;
  for (int i = ty; i < 32; i += 8)
    tile[i][tx] = src[(size_t)(r0 + i) * Ccol + c0 + tx];
  __syncthreads();
  for (int i = ty; i < 32; i += 8)
    dst[(size_t)(c0 + i) * R + r0 + tx] = f2bf(tile[tx][i]);
}

// ---------------- GEMM family ----------------
// A: [*][K] bf16 (x), Bt: [N][K] bf16 (weights, pre-offset for MODE 3).
// 128x128 tile, BK=64, 4 waves, XCD-chunked block swizzle.
// MODE 0: f32 out, stride N (C = A*Bt^T).
// MODE 2: bf16 out, stride QK_STRIDE (QK part of GEMM1).
// MODE 3: V-GEMM with SWAPPED operands -> D is C^T (row = V-col n, col = m);
//         writes vt[(b*12+h)*64 + d][key] coalesced along key.
template <int MODE>
__global__ __launch_bounds__(256) void k_gemm(const short* __restrict__ A,
                                              const short* __restrict__ Bt,
                                              void* __restrict__ Cp,
                                              short* __restrict__ vt,
                                              int Mreal, int N, int K) {
  __shared__ short As[128 * 64];
  __shared__ short Bs[128 * 64];
  // bijective XCD-chunk swizzle (m204): XCD x gets a contiguous wg range
  int nwg = gridDim.x;
  int qq = nwg >> 3, rr = nwg & 7;
  int x8 = blockIdx.x & 7, i8 = blockIdx.x >> 3;
  int wg = (x8 < rr ? x8 * (qq + 1) : rr * (qq + 1) + (x8 - rr) * qq) + i8;
  const int tiles_n = N >> 7;
  int tm = wg / tiles_n, tn = wg % tiles_n;
  int m0 = tm << 7, n0 = tn << 7;
  int lane = threadIdx.x & 63, wave = threadIdx.x >> 6;
  int wr = wave >> 1, wc = wave & 1;
  int l15 = lane & 15, g = lane >> 4;

  f32x4 acc[4][4];
  f32x4 z = {0.f, 0.f, 0.f, 0.f};
#pragma unroll
  for (int i = 0; i < 4; ++i)
#pragma unroll
    for (int j = 0; j < 4; ++j) acc[i][j] = z;

  int arow = lane >> 3;          // 0..7 rows within 8-row chunk
  int acol = (lane & 7) * 8;     // elem offset within 64

  for (int k0 = 0; k0 < K; k0 += 64) {
    __syncthreads();
#pragma unroll
    for (int cc = 0; cc < 4; ++cc) {
      int rb = (cc * 4 + wave) * 8;  // wave-uniform row base
      gload_lds16(A + (size_t)(m0 + rb + arow) * K + (k0 + acol),
                  (char*)As + rb * 128);
      gload_lds16(Bt + (size_t)(n0 + rb + arow) * K + (k0 + acol),
                  (char*)Bs + rb * 128);
    }
    __syncthreads();
#pragma unroll
    for (int ks = 0; ks < 2; ++ks) {
      short8 a[4], b[4];
      if (MODE == 3) {
        // swapped: A-operand from weight tile (n-dim rows), B-operand from x tile
#pragma unroll
        for (int nf = 0; nf < 4; ++nf)
          a[nf] = *(const short8*)&Bs[(wr * 64 + nf * 16 + l15) * 64 + ks * 32 + g * 8];
#pragma unroll
        for (int mf = 0; mf < 4; ++mf)
          b[mf] = *(const short8*)&As[(wc * 64 + mf * 16 + l15) * 64 + ks * 32 + g * 8];
      } else {
#pragma unroll
        for (int mf = 0; mf < 4; ++mf)
          a[mf] = *(const short8*)&As[(wr * 64 + mf * 16 + l15) * 64 + ks * 32 + g * 8];
#pragma unroll
        for (int nf = 0; nf < 4; ++nf)
          b[nf] = *(const short8*)&Bs[(wc * 64 + nf * 16 + l15) * 64 + ks * 32 + g * 8];
      }
#pragma unroll
      for (int i = 0; i < 4; ++i)
#pragma unroll
        for (int j = 0; j < 4; ++j)
          acc[i][j] = __builtin_amdgcn_mfma_f32_16x16x32_bf16(a[i], b[j], acc[i][j], 0, 0, 0);
    }
  }

  // D layout (m89-verified): row = g*4+reg, col = l15
  if (MODE == 3) {
    // acc[nf][mf]: D row = V-col n (h*64+d), D col = token m
#pragma unroll
    for (int nf = 0; nf < 4; ++nf) {
#pragma unroll
      for (int reg = 0; reg < 4; ++reg) {
        int n = n0 + wr * 64 + nf * 16 + g * 4 + reg;  // 0..767
        int h = n >> 6, d = n & 63;
        size_t rbase = ((size_t)(h)) * HD;  // b-dependent part added per element
#pragma unroll
        for (int mf = 0; mf < 4; ++mf) {
          int m = m0 + wc * 64 + mf * 16 + l15;
          if (m >= Mreal) continue;
          int bb = (unsigned)m / 641u;
          int key = m - bb * 641;
          vt[((size_t)(bb * H_SZ + h) * HD + d) * VT_STRIDE + key] = f2bf(acc[nf][mf][reg]);
        }
      }
    }
    return;
  }
#pragma unroll
  for (int mf = 0; mf < 4; ++mf) {
#pragma unroll
    for (int reg = 0; reg < 4; ++reg) {
      int m = m0 + wr * 64 + mf * 16 + g * 4 + reg;
      if (m >= Mreal) continue;
#pragma unroll
      for (int nf = 0; nf < 4; ++nf) {
        int n = n0 + wc * 64 + nf * 16 + l15;
        float v = acc[mf][nf][reg];
        if (MODE == 2)
          ((unsigned short*)Cp)[(size_t)m * QK_STRIDE + n] = f2bf(v);
        else
          ((float*)Cp)[(size_t)m * N + n] = v;
      }
    }
  }
}

// ---------------- fused masked attention ----------------
// grid: B*H*NQT = 4224 blocks (8*528, XCD-swizzled), 256 threads (4 waves x 16 q-rows)
__global__ __launch_bounds__(256) void k_attn(const short* __restrict__ qk,  // [M][1536]
                                              const short* __restrict__ vt,  // [384*64][648]
                                              short* __restrict__ y) {       // [M_PAD][768]
  __shared__ short Ks[64 * 72];       // K tile row-major [key][d]
  __shared__ short Vt[64 * 72];       // V^T tile [d][key]
  __shared__ short Ps[4][16 * 72];    // per-wave P [q][key]

  int bid = blockIdx.x;
  int work = (bid & 7) * 528 + (bid >> 3);
  int qt = work % NQT;
  int rem = work / NQT;
  int h = rem % H_SZ;
  int b = rem / H_SZ;
  int q0 = qt * 64;
  int lane = threadIdx.x & 63, w = threadIdx.x >> 6;
  int l15 = lane & 15, g = lane >> 4;

  // Q fragments in registers (A-frag: row = l15, k = g*8+i, per 32-wide kstep)
  size_t qbase = (size_t)(b * L_SZ + q0 + w * 16 + l15) * QK_STRIDE + h * HD;
  short8 qa[2];
#pragma unroll
  for (int ks = 0; ks < 2; ++ks)
    qa[ks] = *(const short8*)&qk[qbase + ks * 32 + g * 8];

  f32x4 o[4];
  float m_run[4], l_run[4];
  f32x4 z = {0.f, 0.f, 0.f, 0.f};
#pragma unroll
  for (int df = 0; df < 4; ++df) o[df] = z;
#pragma unroll
  for (int r = 0; r < 4; ++r) { m_run[r] = -1e30f; l_run[r] = 0.f; }

  // per-row mask bound, hoisted: valid j <= jmax[reg]
  int jmax[4];
#pragma unroll
  for (int reg = 0; reg < 4; ++reg) {
    int i = q0 + w * 16 + g * 4 + reg;
    jmax[reg] = (i == MEMK) ? (L_SZ - 1) : (i < MEMK ? MEMK : i);
  }

  int q1 = q0 + 63; if (q1 > L_SZ - 1) q1 = L_SZ - 1;
  int col_max = (q0 <= MEMK && MEMK <= q1) ? (L_SZ - 1) : (q1 < MEMK ? MEMK : q1);

  size_t kbase = (size_t)b * L_SZ * QK_STRIDE + C_SZ + h * HD;
  size_t vbase = (size_t)(b * H_SZ + h) * HD * VT_STRIDE;

  for (int c0 = 0; c0 <= col_max; c0 += 64) {
    __syncthreads();
    // stage K rows [c0, c0+64): coalesced short8
#pragma unroll
    for (int it = 0; it < 2; ++it) {
      int idx = threadIdx.x + it * 256;
      int kk = idx >> 3, j = (idx & 7) * 8;
      *(short8*)&Ks[kk * 72 + j] =
          *(const short8*)&qk[kbase + (size_t)(c0 + kk) * QK_STRIDE + j];
    }
    // stage V^T from pre-transposed global: symmetric with K
#pragma unroll
    for (int it = 0; it < 2; ++it) {
      int idx = threadIdx.x + it * 256;
      int d = idx >> 3, key0 = (idx & 7) * 8;
      *(short8*)&Vt[d * 72 + key0] =
          *(const short8*)&vt[vbase + (size_t)d * VT_STRIDE + c0 + key0];
    }
    __syncthreads();

    // S = Q K^T  (D: row=q=g*4+reg, col=key=l15 within each 16-wide kf frag)
    f32x4 s[4];
#pragma unroll
    for (int kf = 0; kf < 4; ++kf) {
      f32x4 sa = z;
#pragma unroll
      for (int ks = 0; ks < 2; ++ks) {
        short8 kb = *(const short8*)&Ks[(kf * 16 + l15) * 72 + ks * 32 + g * 8];
        sa = __builtin_amdgcn_mfma_f32_16x16x32_bf16(qa[ks], kb, sa, 0, 0, 0);
      }
      s[kf] = sa;
    }

    // mask + scale into log2 domain
#pragma unroll
    for (int kf = 0; kf < 4; ++kf) {
      int j = c0 + kf * 16 + l15;
#pragma unroll
      for (int reg = 0; reg < 4; ++reg)
        s[kf][reg] = (j <= jmax[reg]) ? s[kf][reg] * SCL_LOG2E : -1e30f;
    }

    // online softmax in exp2 domain (stats per row; keys spread over 16-lane group)
    float corr[4];
#pragma unroll
    for (int reg = 0; reg < 4; ++reg) {
      float t = fmaxf(fmaxf(s[0][reg], s[1][reg]), fmaxf(s[2][reg], s[3][reg]));
      t = fmaxf(t, __shfl_xor(t, 1));
      t = fmaxf(t, __shfl_xor(t, 2));
      t = fmaxf(t, __shfl_xor(t, 4));
      t = fmaxf(t, __shfl_xor(t, 8));
      float mn = fmaxf(m_run[reg], t);
      corr[reg] = exp2f(m_run[reg] - mn);
      m_run[reg] = mn;
    }
#pragma unroll
    for (int kf = 0; kf < 4; ++kf)
#pragma unroll
      for (int reg = 0; reg < 4; ++reg)
        s[kf][reg] = exp2f(s[kf][reg] - m_run[reg]);
#pragma unroll
    for (int reg = 0; reg < 4; ++reg) {
      float ls = s[0][reg] + s[1][reg] + s[2][reg] + s[3][reg];
      ls += __shfl_xor(ls, 1);
      ls += __shfl_xor(ls, 2);
      ls += __shfl_xor(ls, 4);
      ls += __shfl_xor(ls, 8);
      l_run[reg] = l_run[reg] * corr[reg] + ls;
      o[0][reg] *= corr[reg];
      o[1][reg] *= corr[reg];
      o[2][reg] *= corr[reg];
      o[3][reg] *= corr[reg];
    }

    // P -> per-wave LDS (bf16); in-wave write->read ordered by lgkmcnt, no barrier
#pragma unroll
    for (int kf = 0; kf < 4; ++kf)
#pragma unroll
      for (int reg = 0; reg < 4; ++reg)
        Ps[w][(g * 4 + reg) * 72 + kf * 16 + l15] = (short)f2bf(s[kf][reg]);

    short8 pa[2];
#pragma unroll
    for (int ks = 0; ks < 2; ++ks)
      pa[ks] = *(const short8*)&Ps[w][l15 * 72 + ks * 32 + g * 8];
#pragma unroll
    for (int df = 0; df < 4; ++df) {
#pragma unroll
      for (int ks = 0; ks < 2; ++ks) {
        short8 vb = *(const short8*)&Vt[(df * 16 + l15) * 72 + ks * 32 + g * 8];
        o[df] = __builtin_amdgcn_mfma_f32_16x16x32_bf16(pa[ks], vb, o[df], 0, 0, 0);
      }
    }
  }

  // epilogue
#pragma unroll
  for (int reg = 0; reg < 4; ++reg) {
    int i = q0 + w * 16 + g * 4 + reg;
    if (i >= L_SZ) continue;
    float inv = 1.0f / l_run[reg];
#pragma unroll
    for (int df = 0; df < 4; ++df)
      y[(size_t)(b * L_SZ + i) * C_SZ + h * HD + df * 16 + l15] = (short)f2bf(o[df][reg] * inv);
  }
}

// ---------------- launch ----------------
extern "C" void kernel_launch(void* const* d_in, const int* in_sizes, int n_in,
                              void* d_out, int out_size, void* d_ws, size_t ws_size,
                              hipStream_t stream) {
  const float* x = (const float*)d_in[0];
  const float* Wa = (const float*)d_in[1];
  const float* Wp = (const float*)d_in[2];
  float* out = (float*)d_out;

  char* ws = (char*)d_ws;
  size_t off0 = 0;
  short* x_bf = (short*)(ws + off0);                       // [M_PAD][768], reused as y
  size_t off1 = off0 + (size_t)M_PAD * C_SZ * 2;
  short* Wa_t = (short*)(ws + off1);                       // [2304][768]
  size_t off2 = off1 + (size_t)N_QKV * C_SZ * 2;
  short* Wp_t = (short*)(ws + off2);                       // [768][768]
  size_t off3 = off2 + (size_t)C_SZ * C_SZ * 2;
  short* qk = (short*)(ws + off3);                         // [M_REAL][1536] (Q,K only)
  size_t off4 = off3 + (size_t)M_REAL * QK_STRIDE * 2;
  short* vt = (short*)(ws + off4);                         // [384*64][648] V transposed
  size_t need = off4 + (size_t)B_SZ * H_SZ * HD * VT_STRIDE * 2 + 4096;  // slack for
  if (ws_size < need) return;  // ~131.2 MB             // masked OOB-in-row reads

  int n4 = M_REAL * C_SZ / 4;
  k_conv_x<<<(n4 + 255) / 256, 256, 0, stream>>>(x, (unsigned short*)x_bf, n4);
  k_transpose_bf16<<<dim3(N_QKV / 32, C_SZ / 32), 256, 0, stream>>>(Wa, (unsigned short*)Wa_t, C_SZ, N_QKV);
  k_transpose_bf16<<<dim3(C_SZ / 32, C_SZ / 32), 256, 0, stream>>>(Wp, (unsigned short*)Wp_t, C_SZ, C_SZ);

  // GEMM1 split: QK (coalesced bf16 epilogue) + V (swapped-operand, writes vt)
  k_gemm<2><<<(M_PAD / 128) * (QK_STRIDE / 128), 256, 0, stream>>>(x_bf, Wa_t, (void*)qk, nullptr, M_REAL, QK_STRIDE, C_SZ);
  k_gemm<3><<<(M_PAD / 128) * (C_SZ / 128), 256, 0, stream>>>(x_bf, Wa_t + (size_t)QK_STRIDE * C_SZ, nullptr, vt, M_REAL, C_SZ, C_SZ);
  k_attn<<<B_SZ * H_SZ * NQT, 256, 0, stream>>>(qk, vt, x_bf /* y reuses x_bf */);
  k_gemm<0><<<(M_PAD / 128) * (C_SZ / 128), 256, 0, stream>>>(x_bf, Wp_t, (void*)out, nullptr, M_REAL, C_SZ, C_SZ);
}